// Round 2
// baseline (173.110 us; speedup 1.0000x reference)
//
#include <hip/hip_runtime.h>

// KnnExpansion: out[f, n] = sum_k alpha[i[n,k], f] * exp(-0.5 * d[n,k] / sigma^2)
// N=131072 queries, K=32 neighbors, M=65536 alpha rows, F=64 channels.
//
// Mapping: one wave (64 lanes) per query-PAIR; lane = channel f.
//  - alpha row gather: coalesced 256B load (64 lanes x 4B), base broadcast
//    via readlane -> SGPR, weight multiplier also SGPR.
//  - d/i for a pair of queries = 64 contiguous words -> ONE coalesced
//    wave-load each; exp computed on all 64 lanes (no divergence).
//  - TWO independent FMA chains per k-loop -> up to 64 gathers in flight
//    (memory-level parallelism; the gathers are L2-miss/L3-hit, ~700cy).
//  - 64x64 output tile transposed through LDS for coalesced [F, N] stores.

#define N_Q 131072
#define K_NB 32
#define F_CH 64

__global__ __launch_bounds__(256) void knn_exp_kernel(
    const float* __restrict__ dmat,   // [N, 32]
    const int*   __restrict__ imat,   // [N, 32]
    const float* __restrict__ alpha,  // [65536, 64]
    const float* __restrict__ sigma,  // [1]
    float*       __restrict__ out)    // [64, N]
{
    __shared__ float tile[64][65];    // +1 pad: conflict-free column reads

    const int lane = threadIdx.x & 63;
    const int wave = threadIdx.x >> 6;
    const int n0   = blockIdx.x * 64;   // 64 queries per block

    const float s = sigma[0];
    const float c = -0.5f / (s * s);

    // Each wave: 16 queries, processed as 8 pairs.
    for (int p = 0; p < 8; ++p) {
        const int q0 = wave * 16 + p * 2;   // block-local query of the pair
        const int n  = n0 + q0;             // global query index (even)

        // d/i for queries n and n+1: 64 contiguous elements each.
        // Lanes 0..31 -> query n, lanes 32..63 -> query n+1.
        const float dv = dmat[(size_t)n * K_NB + lane];
        const int   iv = imat[(size_t)n * K_NB + lane];
        const float wv = __expf(c * dv);

        float acc0 = 0.0f;
        float acc1 = 0.0f;
        #pragma unroll
        for (int k = 0; k < K_NB; ++k) {
            // compile-time lane index -> v_readlane -> SGPR broadcast
            const float wk0 = __int_as_float(
                __builtin_amdgcn_readlane(__float_as_int(wv), k));
            const int   ik0 = __builtin_amdgcn_readlane(iv, k);
            const float wk1 = __int_as_float(
                __builtin_amdgcn_readlane(__float_as_int(wv), 32 + k));
            const int   ik1 = __builtin_amdgcn_readlane(iv, 32 + k);
            // two independent chains -> 2x loads in flight
            acc0 = fmaf(wk0, alpha[(size_t)ik0 * F_CH + lane], acc0);
            acc1 = fmaf(wk1, alpha[(size_t)ik1 * F_CH + lane], acc1);
        }
        tile[q0][lane]     = acc0;
        tile[q0 + 1][lane] = acc1;
    }

    __syncthreads();

    // Transposed, coalesced store: each wave writes 16 channel-rows,
    // each row = 64 contiguous floats of out[f, n0..n0+63].
    #pragma unroll
    for (int fi = 0; fi < 16; ++fi) {
        const int f = wave * 16 + fi;
        out[(size_t)f * N_Q + n0 + lane] = tile[lane][f];
    }
}

extern "C" void kernel_launch(void* const* d_in, const int* in_sizes, int n_in,
                              void* d_out, int out_size, void* d_ws, size_t ws_size,
                              hipStream_t stream) {
    const float* dmat  = (const float*)d_in[0];
    const int*   imat  = (const int*)d_in[1];
    const float* alpha = (const float*)d_in[2];
    const float* sigma = (const float*)d_in[3];
    float* out = (float*)d_out;

    dim3 grid(N_Q / 64);   // 2048 blocks
    dim3 block(256);       // 4 waves
    hipLaunchKernelGGL(knn_exp_kernel, grid, block, 0, stream,
                       dmat, imat, alpha, sigma, out);
}

// Round 3
// 127.337 us; speedup vs baseline: 1.3595x; 1.3595x over previous
//
#include <hip/hip_runtime.h>

// KnnExpansion: out[f, n] = sum_k alpha[i[n,k], f] * exp(-0.5 * d[n,k] / sigma^2)
// N=131072 queries, K=32 neighbors, M=65536 alpha rows, F=64 channels.
//
// Latency-bound on the random alpha-row gather (L2-miss -> L3, ~700cy).
// Strategy: one wave per query, lane = channel f. Force 32 outstanding
// gathers per wave:
//   issue loop  : g[k] = alpha[ik*64 + lane]  (compile-time-indexed array
//                 -> stays in VGPRs; 32 global_load_dword issued back-to-back)
//   sched_barrier(0) : stop LLVM sinking the loads down to their uses
//                 (round-2 lesson: it otherwise serializes at vmcnt(0) each)
//   consume loop: s_waitcnt vmcnt(31..0) drains incrementally into FMAs.
// Gather base + weight are SGPRs via compile-time readlane broadcasts.
// 64x64 output tile transposed through LDS for coalesced [F, N] stores.

#define N_Q 131072
#define K_NB 32
#define F_CH 64

__global__ __launch_bounds__(256) void knn_exp_kernel(
    const float* __restrict__ dmat,   // [N, 32]
    const int*   __restrict__ imat,   // [N, 32]
    const float* __restrict__ alpha,  // [65536, 64]
    const float* __restrict__ sigma,  // [1]
    float*       __restrict__ out)    // [64, N]
{
    __shared__ float tile[64][65];    // +1 pad: conflict-free column reads

    const int lane = threadIdx.x & 63;
    const int wave = threadIdx.x >> 6;
    const int n0   = blockIdx.x * 64;   // 64 queries per block

    const float s = sigma[0];
    const float c = -0.5f / (s * s);

    for (int qi = 0; qi < 16; ++qi) {
        const int q = wave * 16 + qi;
        const int n = n0 + q;

        // lanes 0..31: d -> Gaussian weight; lanes 32..63: neighbor index.
        float wv = 0.0f;
        int   iv = 0;
        if (lane < 32) {
            wv = __expf(c * dmat[(size_t)n * K_NB + lane]);
        } else {
            iv = imat[(size_t)n * K_NB + (lane - 32)];
        }

        // ---- issue all 32 gathers (no consumption in between) ----
        float g[K_NB];
        #pragma unroll
        for (int k = 0; k < K_NB; ++k) {
            const int ik = __builtin_amdgcn_readlane(iv, 32 + k);  // SGPR
            g[k] = alpha[(size_t)ik * F_CH + lane];  // coalesced 256B row
        }

        // keep the loads issued as a batch; consumers may not hoist above
        __builtin_amdgcn_sched_barrier(0);

        // ---- consume: waitcnt drains incrementally, 4-way acc chain ----
        float a0 = 0.0f, a1 = 0.0f, a2 = 0.0f, a3 = 0.0f;
        #pragma unroll
        for (int k = 0; k < K_NB; k += 4) {
            const float w0 = __int_as_float(
                __builtin_amdgcn_readlane(__float_as_int(wv), k + 0));
            const float w1 = __int_as_float(
                __builtin_amdgcn_readlane(__float_as_int(wv), k + 1));
            const float w2 = __int_as_float(
                __builtin_amdgcn_readlane(__float_as_int(wv), k + 2));
            const float w3 = __int_as_float(
                __builtin_amdgcn_readlane(__float_as_int(wv), k + 3));
            a0 = fmaf(w0, g[k + 0], a0);
            a1 = fmaf(w1, g[k + 1], a1);
            a2 = fmaf(w2, g[k + 2], a2);
            a3 = fmaf(w3, g[k + 3], a3);
        }
        tile[q][lane] = (a0 + a1) + (a2 + a3);
    }

    __syncthreads();

    // Transposed, coalesced store: each wave writes 16 channel-rows,
    // each row = 64 contiguous floats of out[f, n0..n0+63].
    #pragma unroll
    for (int fi = 0; fi < 16; ++fi) {
        const int f = wave * 16 + fi;
        out[(size_t)f * N_Q + n0 + lane] = tile[lane][f];
    }
}

extern "C" void kernel_launch(void* const* d_in, const int* in_sizes, int n_in,
                              void* d_out, int out_size, void* d_ws, size_t ws_size,
                              hipStream_t stream) {
    const float* dmat  = (const float*)d_in[0];
    const int*   imat  = (const int*)d_in[1];
    const float* alpha = (const float*)d_in[2];
    const float* sigma = (const float*)d_in[3];
    float* out = (float*)d_out;

    dim3 grid(N_Q / 64);   // 2048 blocks
    dim3 block(256);       // 4 waves
    hipLaunchKernelGGL(knn_exp_kernel, grid, block, 0, stream,
                       dmat, imat, alpha, sigma, out);
}

// Round 4
// 69.276 us; speedup vs baseline: 2.4989x; 1.8381x over previous
//
#include <hip/hip_runtime.h>
#include <hip/hip_fp16.h>

// KnnExpansion: out[f, n] = sum_k alpha[i[n,k], f] * exp(-0.5 * d[n,k] / sigma^2)
// N=131072 queries, K=32 neighbors, M=65536 alpha rows, F=64 channels.
//
// Rounds 1-3 converge at ~127us with demand-side gather BW of 8.3 TB/s and a
// 3.6 TB/s L2-miss plateau -> bandwidth-bound on the random alpha gather,
// not latency-bound. Lever: halve gather bytes. Pre-pass converts alpha to
// fp16 in d_ws (8 MiB, fits L2 better too), main kernel gathers 128B rows.
//
// Mapping (main): one wave per query, lane = channel f.
//  - alpha16 row gather: coalesced 128B load (64 lanes x 2B)
//  - w[k]/idx[k] broadcast via compile-time readlane -> SGPR base + SGPR mult
//  - 64x64 output tile transposed through LDS for coalesced [F, N] stores.

#define N_Q    131072
#define K_NB   32
#define F_CH   64
#define M_ROWS 65536

// ---- pre-pass: alpha f32 -> f16 into workspace (streaming, ~4us) ----
__global__ __launch_bounds__(256) void cvt_alpha_f16(
    const float* __restrict__ alpha, __half* __restrict__ a16)
{
    // M*F = 4,194,304 elements; 8 per thread; 524,288 threads
    const int t = blockIdx.x * 256 + threadIdx.x;
    const float4 v0 = ((const float4*)alpha)[(size_t)t * 2 + 0];
    const float4 v1 = ((const float4*)alpha)[(size_t)t * 2 + 1];
    union { __half2 h2[4]; uint4 u; } pk;
    pk.h2[0] = __floats2half2_rn(v0.x, v0.y);
    pk.h2[1] = __floats2half2_rn(v0.z, v0.w);
    pk.h2[2] = __floats2half2_rn(v1.x, v1.y);
    pk.h2[3] = __floats2half2_rn(v1.z, v1.w);
    ((uint4*)a16)[t] = pk.u;
}

// ---- main kernel: fp16 gather ----
__global__ __launch_bounds__(256) void knn_exp_f16(
    const float*  __restrict__ dmat,   // [N, 32]
    const int*    __restrict__ imat,   // [N, 32]
    const __half* __restrict__ a16,    // [65536, 64] fp16
    const float*  __restrict__ sigma,  // [1]
    float*        __restrict__ out)    // [64, N]
{
    __shared__ float tile[64][65];     // +1 pad: conflict-free column reads

    const int lane = threadIdx.x & 63;
    const int wave = threadIdx.x >> 6;
    const int n0   = blockIdx.x * 64;  // 64 queries per block

    const float s = sigma[0];
    const float c = -0.5f / (s * s);

    for (int qi = 0; qi < 16; ++qi) {
        const int q = wave * 16 + qi;
        const int n = n0 + q;

        // lanes 0..31: d -> Gaussian weight; lanes 32..63: neighbor index.
        float wv = 0.0f;
        int   iv = 0;
        if (lane < 32) {
            wv = __expf(c * dmat[(size_t)n * K_NB + lane]);
        } else {
            iv = imat[(size_t)n * K_NB + (lane - 32)];
        }

        float a0 = 0.0f, a1 = 0.0f, a2 = 0.0f, a3 = 0.0f;
        #pragma unroll
        for (int k = 0; k < K_NB; k += 4) {
            const float w0 = __int_as_float(
                __builtin_amdgcn_readlane(__float_as_int(wv), k + 0));
            const int   i0 = __builtin_amdgcn_readlane(iv, 32 + k + 0);
            const float w1 = __int_as_float(
                __builtin_amdgcn_readlane(__float_as_int(wv), k + 1));
            const int   i1 = __builtin_amdgcn_readlane(iv, 32 + k + 1);
            const float w2 = __int_as_float(
                __builtin_amdgcn_readlane(__float_as_int(wv), k + 2));
            const int   i2 = __builtin_amdgcn_readlane(iv, 32 + k + 2);
            const float w3 = __int_as_float(
                __builtin_amdgcn_readlane(__float_as_int(wv), k + 3));
            const int   i3 = __builtin_amdgcn_readlane(iv, 32 + k + 3);
            // coalesced 128B row gathers (64 lanes x 2B), 4 indep chains
            a0 = fmaf(w0, __half2float(a16[(size_t)i0 * F_CH + lane]), a0);
            a1 = fmaf(w1, __half2float(a16[(size_t)i1 * F_CH + lane]), a1);
            a2 = fmaf(w2, __half2float(a16[(size_t)i2 * F_CH + lane]), a2);
            a3 = fmaf(w3, __half2float(a16[(size_t)i3 * F_CH + lane]), a3);
        }
        tile[q][lane] = (a0 + a1) + (a2 + a3);
    }

    __syncthreads();

    // Transposed, coalesced store: each wave writes 16 channel-rows,
    // each row = 64 contiguous floats of out[f, n0..n0+63].
    #pragma unroll
    for (int fi = 0; fi < 16; ++fi) {
        const int f = wave * 16 + fi;
        out[(size_t)f * N_Q + n0 + lane] = tile[lane][f];
    }
}

// ---- fallback (fp32 gather, round-1 kernel) if ws too small ----
__global__ __launch_bounds__(256) void knn_exp_f32(
    const float* __restrict__ dmat,
    const int*   __restrict__ imat,
    const float* __restrict__ alpha,
    const float* __restrict__ sigma,
    float*       __restrict__ out)
{
    __shared__ float tile[64][65];
    const int lane = threadIdx.x & 63;
    const int wave = threadIdx.x >> 6;
    const int n0   = blockIdx.x * 64;
    const float s = sigma[0];
    const float c = -0.5f / (s * s);

    for (int qi = 0; qi < 16; ++qi) {
        const int q = wave * 16 + qi;
        const int n = n0 + q;
        float wv = 0.0f;
        int   iv = 0;
        if (lane < 32) {
            wv = __expf(c * dmat[(size_t)n * K_NB + lane]);
        } else {
            iv = imat[(size_t)n * K_NB + (lane - 32)];
        }
        float acc = 0.0f;
        #pragma unroll
        for (int k = 0; k < K_NB; ++k) {
            const float wk = __int_as_float(
                __builtin_amdgcn_readlane(__float_as_int(wv), k));
            const int   ik = __builtin_amdgcn_readlane(iv, 32 + k);
            acc = fmaf(wk, alpha[(size_t)ik * F_CH + lane], acc);
        }
        tile[q][lane] = acc;
    }
    __syncthreads();
    #pragma unroll
    for (int fi = 0; fi < 16; ++fi) {
        const int f = wave * 16 + fi;
        out[(size_t)f * N_Q + n0 + lane] = tile[lane][f];
    }
}

extern "C" void kernel_launch(void* const* d_in, const int* in_sizes, int n_in,
                              void* d_out, int out_size, void* d_ws, size_t ws_size,
                              hipStream_t stream) {
    const float* dmat  = (const float*)d_in[0];
    const int*   imat  = (const int*)d_in[1];
    const float* alpha = (const float*)d_in[2];
    const float* sigma = (const float*)d_in[3];
    float* out = (float*)d_out;

    const size_t need = (size_t)M_ROWS * F_CH * sizeof(__half);  // 8 MiB

    if (ws_size >= need) {
        __half* a16 = (__half*)d_ws;
        // 4,194,304 elems / 8 per thread / 256 per block = 2048 blocks
        hipLaunchKernelGGL(cvt_alpha_f16, dim3(M_ROWS * F_CH / 8 / 256),
                           dim3(256), 0, stream, alpha, a16);
        hipLaunchKernelGGL(knn_exp_f16, dim3(N_Q / 64), dim3(256), 0, stream,
                           dmat, imat, a16, sigma, out);
    } else {
        hipLaunchKernelGGL(knn_exp_f32, dim3(N_Q / 64), dim3(256), 0, stream,
                           dmat, imat, alpha, sigma, out);
    }
}